// Round 11
// baseline (393.937 us; speedup 1.0000x reference)
//
#include <hip/hip_runtime.h>
#include <hip/hip_fp16.h>

// NNUE forward: out = MLP(clip(concat(Wf@w_in^T+b, Bf@w_in^T+b)))
// Big GEMM: M=8192, N=256, K=40960, HBM-bound on the 1.31 GB A stream.
// fp16 MFMA 16x16x32, f32 accumulate.
//
// v9 "flatmm" (r10 post-mortem: v7(128B)=v8(512B)=382us -> burst length
// irrelevant; the A LDS round-trip serialized under barriers is the ~40%
// overhead). A goes global->VGPR->cvt->MFMA directly: each wave owns a
// 16-row strip and the FULL N=256 (16 accs = 64 VGPR), so its A fragment
// (lane = row lane&15, k-halves (lane>>4)*8) is loaded as 8 consecutive
// floats/lane. No A-LDS, no A-barrier. W: pre-swizzled f16 image staged
// via global_load_lds (3 x 16KB bufs), one lgkmcnt-barrier per K-step;
// cvt's compiler-counted vmcnt wait on A(t) auto-drains older W(t+1).
// 8 waves/block (BM=128), KS=8 -> 512 blocks, 2/CU; ks=blockIdx&7 = XCD.

#define FEAT 40960
#define PSTRIDE (8192ull * 256ull)
#define KSPLIT 8
#define KCHUNK (FEAT / KSPLIT)   // 5120
#define NSTEP 160
#define WTILE_BYTES 16384        // 256 rows x 32 k x f16, swizzled
#define WWS_BYTES (1280ull * WTILE_BYTES)   // 20 MB

using floatx4 = __attribute__((ext_vector_type(4))) float;
using half8   = __attribute__((ext_vector_type(8))) _Float16;

// ---------------------------------------------------------------------------
// W pre-pass: w_in f32 [256][40960] -> Wws f16, 1280 chunks of 16 KB, each
// the exact swizzled LDS image for one K-step: byte(r, granule g) =
// T*16384 + r*64 + ((g ^ ((r>>1)&3))*16), granule = 8 consecutive k-halves.
// T = ks*160 + t (ks-major).
// ---------------------------------------------------------------------------
__global__ __launch_bounds__(256) void nnue_wprep(
    const float* __restrict__ w_in, _Float16* __restrict__ Wws)
{
    const int bid = blockIdx.x;                       // 1280
    const int T   = (bid & 7) * NSTEP + (bid >> 3);
    char* base = (char*)Wws + (size_t)T * WTILE_BYTES;
    const int tid = threadIdx.x;
    const int kg0 = T * 32;
#pragma unroll
    for (int i = 0; i < 4; ++i) {
        const int G = tid + i * 256;                  // 0..1023
        const int r = G >> 2, g = G & 3;
        const float* src = w_in + (size_t)r * FEAT + kg0 + g * 8;
        floatx4 v0 = *reinterpret_cast<const floatx4*>(src);
        floatx4 v1 = *reinterpret_cast<const floatx4*>(src + 4);
        half8 h;
#pragma unroll
        for (int j = 0; j < 4; ++j) { h[j] = (_Float16)v0[j]; h[4 + j] = (_Float16)v1[j]; }
        *reinterpret_cast<half8*>(base + r * 64 + ((g ^ ((r >> 1) & 3)) << 4)) = h;
    }
}

// ---------------------------------------------------------------------------
// Primary GEMM: 512 thr = 8 waves, wave strip = 16 rows x 256 cols.
// ---------------------------------------------------------------------------
template <typename PT>
__global__ __launch_bounds__(512, 4) void nnue_gemm_v9(
    const float* __restrict__ white, const float* __restrict__ black,
    const _Float16* __restrict__ Wws, PT* __restrict__ P)
{
    __shared__ __align__(16) _Float16 Ws[3][256 * 32];   // 48 KB

    const int tid  = threadIdx.x;
    const int lane = tid & 63;
    const int wave = tid >> 6;    // 0..7

    const int ks = blockIdx.x & 7;    // == XCD index (round-robin dispatch)
    const int mb = blockIdx.x >> 3;   // 0..63

    const float* Abase = (mb < 32)
        ? (white + (size_t)mb * 128 * FEAT)
        : (black + (size_t)(mb - 32) * 128 * FEAT);
    const int k0 = ks * KCHUNK;

    const int frow = lane & 15;
    const int fhi  = lane >> 4;

    // A: per-lane row = wave*16 + frow, k window = k0 + t*32 + fhi*8 (8 floats)
    const float* Aptr = Abase + (size_t)(wave * 16 + frow) * FEAT + fhi * 8 + k0;

    // W LDS read: bf[n] at row r=n*16+frow, byte = r*64 + ((fhi*16)^swz(r));
    // swz(r) = ((r>>1)&3)<<4 == ((frow>>1)&3)<<4 since n*16>>1 is mult of 8.
    const int kb = (fhi * 16) ^ (((frow >> 1) & 3) << 4);

    // W async staging: per-lane global src (pre-swizzled), wave-linear LDS
    const char* wsrc0 = (const char*)Wws + (size_t)(ks * NSTEP) * WTILE_BYTES
                        + wave * 2048 + lane * 16;

    floatx4 acc[16];
    const floatx4 zero = {0.f, 0.f, 0.f, 0.f};
#pragma unroll
    for (int n = 0; n < 16; ++n) acc[n] = zero;

    floatx4 raA0, raA1, raB0, raB1;   // two statically-named A prefetch sets

    auto issueW = [&](int t, int wb) {
        const char* g = wsrc0 + (size_t)t * WTILE_BYTES;
        char* l = (char*)&Ws[wb][0] + wave * 2048;
        __builtin_amdgcn_global_load_lds(
            (const __attribute__((address_space(1))) unsigned int*)g,
            (__attribute__((address_space(3))) unsigned int*)l, 16, 0, 0);
        __builtin_amdgcn_global_load_lds(
            (const __attribute__((address_space(1))) unsigned int*)(g + 1024),
            (__attribute__((address_space(3))) unsigned int*)(l + 1024), 16, 0, 0);
    };

    auto cvt = [&](const floatx4& a0, const floatx4& a1) {
        half8 h;
#pragma unroll
        for (int j = 0; j < 4; ++j) { h[j] = (_Float16)a0[j]; h[4 + j] = (_Float16)a1[j]; }
        return h;
    };

    auto mfmaStep = [&](int wb, half8 af) {
        const char* wbase = (const char*)&Ws[wb][0];
#pragma unroll
        for (int n = 0; n < 16; ++n) {
            half8 bf = *reinterpret_cast<const half8*>(
                wbase + (n * 16 + frow) * 64 + kb);
            acc[n] = __builtin_amdgcn_mfma_f32_16x16x32_f16(af, bf, acc[n], 0, 0, 0);
        }
    };

    // one step: stage W(t+2); load A(t+1) into nxt; cvt cur=A(t) (compiler
    // vmcnt wait on A(t) drains older W(t+1)); MFMA vs Ws[t%3]; lgkm barrier.
    auto stepf = [&](int t, int wbW, int wbR,
                     floatx4& c0, floatx4& c1, floatx4& n0, floatx4& n1) {
        issueW(t + 2, wbW);
        __builtin_amdgcn_sched_barrier(0);
        n0 = *reinterpret_cast<const floatx4*>(Aptr + (size_t)(t + 1) * 32);
        n1 = *reinterpret_cast<const floatx4*>(Aptr + (size_t)(t + 1) * 32 + 4);
        half8 af = cvt(c0, c1);
        mfmaStep(wbR, af);
        asm volatile("s_waitcnt vmcnt(4) lgkmcnt(0)" ::: "memory");
        __builtin_amdgcn_s_barrier();
        __builtin_amdgcn_sched_barrier(0);
    };

    // prologue: W(0),W(1) in flight; A(0) in flight
    issueW(0, 0);
    issueW(1, 1);
    __builtin_amdgcn_sched_barrier(0);
    raA0 = *reinterpret_cast<const floatx4*>(Aptr);
    raA1 = *reinterpret_cast<const floatx4*>(Aptr + 4);
    asm volatile("s_waitcnt vmcnt(4)" ::: "memory");   // W(0) retired
    __builtin_amdgcn_s_barrier();
    __builtin_amdgcn_sched_barrier(0);

    // main: t = 0..155, 26 x 6 (lcm of 3 W-bufs, 2 A-sets)
    for (int tb = 0; tb < 156; tb += 6) {
        stepf(tb + 0, 2, 0, raA0, raA1, raB0, raB1);
        stepf(tb + 1, 0, 1, raB0, raB1, raA0, raA1);
        stepf(tb + 2, 1, 2, raA0, raA1, raB0, raB1);
        stepf(tb + 3, 2, 0, raB0, raB1, raA0, raA1);
        stepf(tb + 4, 0, 1, raA0, raA1, raB0, raB1);
        stepf(tb + 5, 1, 2, raB0, raB1, raA0, raA1);
    }
    stepf(156, 2, 0, raA0, raA1, raB0, raB1);
    stepf(157, 0, 1, raB0, raB1, raA0, raA1);
    // t = 158 (no W issue; reads buf 2; A(159) -> raB)
    raB0 = *reinterpret_cast<const floatx4*>(Aptr + (size_t)159 * 32);
    raB1 = *reinterpret_cast<const floatx4*>(Aptr + (size_t)159 * 32 + 4);
    {
        half8 af = cvt(raA0, raA1);
        mfmaStep(2, af);
    }
    asm volatile("s_waitcnt vmcnt(4) lgkmcnt(0)" ::: "memory");
    __builtin_amdgcn_s_barrier();
    __builtin_amdgcn_sched_barrier(0);
    // t = 159
    {
        half8 af = cvt(raB0, raB1);
        mfmaStep(0, af);
    }

    // epilogue: partial C (pre-bias, pre-clip). row = wave*16+fhi*4+r, col = n*16+frow
    PT* Pb = P + (size_t)ks * PSTRIDE + (size_t)mb * 128 * 256;
#pragma unroll
    for (int n = 0; n < 16; ++n)
#pragma unroll
        for (int r = 0; r < 4; ++r) {
            const int row = wave * 16 + fhi * 4 + r;
            const int col = n * 16 + frow;
            Pb[(size_t)row * 256 + col] = (PT)acc[n][r];
        }
}

// ---------------------------------------------------------------------------
// Tail: reduce KS partials + b_in + clip -> x[.,512], then the 3 tiny layers.
// One block per 32 batch rows.
// ---------------------------------------------------------------------------
template <typename PT>
__global__ __launch_bounds__(256) void nnue_tail(
    const PT* __restrict__ P,
    const float* __restrict__ b_in,
    const float* __restrict__ w_h1, const float* __restrict__ b_h1,
    const float* __restrict__ w_h2, const float* __restrict__ b_h2,
    const float* __restrict__ w_out, const float* __restrict__ b_out,
    float* __restrict__ out)
{
    __shared__ float xs[32][512];
    __shared__ float w1[32][513];
    __shared__ float w2[32][33];
    __shared__ float h1[32][33];
    __shared__ float h2[32][33];
    __shared__ float wo[32];

    const int tid = threadIdx.x;
    const int b0  = blockIdx.x * 32;

    for (int i = tid; i < 32 * 512; i += 256) w1[i >> 9][i & 511] = w_h1[i];
    for (int i = tid; i < 32 * 32; i += 256)  w2[i >> 5][i & 31]  = w_h2[i];
    if (tid < 32) wo[tid] = w_out[tid];

    for (int i = tid; i < 32 * 512; i += 256) {
        const int r = i >> 9, c = i & 511;
        const int persp = c >> 8, n = c & 255;
        const size_t prow = (size_t)(b0 + r) + (persp ? 4096u : 0u);
        float v = 0.f;
#pragma unroll
        for (int s = 0; s < KSPLIT; ++s)
            v += (float)P[(size_t)s * PSTRIDE + prow * 256 + n];
        v += b_in[n];
        xs[r][c] = fminf(fmaxf(v, 0.f), 1.f);
    }
    __syncthreads();

    for (int p = tid; p < 32 * 32; p += 256) {
        const int o = p & 31, r = p >> 5;
        float a = b_h1[o];
        for (int j = 0; j < 512; ++j) a += xs[r][j] * w1[o][j];
        h1[r][o] = fminf(fmaxf(a, 0.f), 1.f);
    }
    __syncthreads();

    for (int p = tid; p < 32 * 32; p += 256) {
        const int o = p & 31, r = p >> 5;
        float a = b_h2[o];
        for (int j = 0; j < 32; ++j) a += h1[r][j] * w2[o][j];
        h2[r][o] = fminf(fmaxf(a, 0.f), 1.f);
    }
    __syncthreads();

    if (tid < 32) {
        float a = b_out[0];
        for (int j = 0; j < 32; ++j) a += h2[tid][j] * wo[j];
        out[b0 + tid] = a;
    }
}

// ---------------------------------------------------------------------------
// Emergency fallback (ws too small): slow but correct, no scratch.
// ---------------------------------------------------------------------------
__global__ __launch_bounds__(256) void nnue_naive(
    const float* __restrict__ white, const float* __restrict__ black,
    const float* __restrict__ w_in, const float* __restrict__ b_in,
    const float* __restrict__ w_h1, const float* __restrict__ b_h1,
    const float* __restrict__ w_h2, const float* __restrict__ b_h2,
    const float* __restrict__ w_out, const float* __restrict__ b_out,
    float* __restrict__ out)
{
    __shared__ float feat[4096];
    __shared__ float xs[512];
    __shared__ float h1s[32];
    __shared__ float h2s[32];
    const int b = blockIdx.x, tid = threadIdx.x;
    float acc0 = 0.f, acc1 = 0.f;
    for (int c = 0; c < FEAT; c += 2048) {
        for (int i = tid; i < 2048; i += 256) {
            feat[i]        = white[(size_t)b * FEAT + c + i];
            feat[2048 + i] = black[(size_t)b * FEAT + c + i];
        }
        __syncthreads();
        const float* wr = w_in + (size_t)tid * FEAT + c;
        for (int k = 0; k < 2048; ++k) {
            const float w = wr[k];
            acc0 += feat[k] * w;
            acc1 += feat[2048 + k] * w;
        }
        __syncthreads();
    }
    xs[tid]       = fminf(fmaxf(acc0 + b_in[tid], 0.f), 1.f);
    xs[256 + tid] = fminf(fmaxf(acc1 + b_in[tid], 0.f), 1.f);
    __syncthreads();
    if (tid < 32) {
        float a = b_h1[tid];
        for (int j = 0; j < 512; ++j) a += xs[j] * w_h1[tid * 512 + j];
        h1s[tid] = fminf(fmaxf(a, 0.f), 1.f);
    }
    __syncthreads();
    if (tid < 32) {
        float a = b_h2[tid];
        for (int j = 0; j < 32; ++j) a += h1s[j] * w_h2[tid * 32 + j];
        h2s[tid] = fminf(fmaxf(a, 0.f), 1.f);
    }
    __syncthreads();
    if (tid == 0) {
        float a = b_out[0];
        for (int j = 0; j < 32; ++j) a += h2s[j] * w_out[j];
        out[b] = a;
    }
}

extern "C" void kernel_launch(void* const* d_in, const int* in_sizes, int n_in,
                              void* d_out, int out_size, void* d_ws, size_t ws_size,
                              hipStream_t stream)
{
    const float* white = (const float*)d_in[0];
    const float* black = (const float*)d_in[1];
    const float* w_in  = (const float*)d_in[2];
    const float* b_in  = (const float*)d_in[3];
    const float* w_h1  = (const float*)d_in[4];
    const float* b_h1  = (const float*)d_in[5];
    const float* w_h2  = (const float*)d_in[6];
    const float* b_h2  = (const float*)d_in[7];
    const float* w_out = (const float*)d_in[8];
    const float* b_out = (const float*)d_in[9];
    float* out = (float*)d_out;

    const size_t pF32 = KSPLIT * PSTRIDE * sizeof(float);     // 64 MB
    const size_t pF16 = KSPLIT * PSTRIDE * sizeof(_Float16);  // 32 MB

    if (ws_size >= pF32 + WWS_BYTES) {
        float* P = (float*)d_ws;
        _Float16* Wws = (_Float16*)((char*)d_ws + pF32);
        nnue_wprep<<<dim3(1280), 256, 0, stream>>>(w_in, Wws);
        nnue_gemm_v9<float><<<dim3(512), 512, 0, stream>>>(white, black, Wws, P);
        nnue_tail<float><<<dim3(128), 256, 0, stream>>>(P, b_in, w_h1, b_h1,
                                                        w_h2, b_h2, w_out, b_out, out);
    } else if (ws_size >= pF16 + WWS_BYTES) {
        _Float16* P = (_Float16*)d_ws;
        _Float16* Wws = (_Float16*)((char*)d_ws + pF16);
        nnue_wprep<<<dim3(1280), 256, 0, stream>>>(w_in, Wws);
        nnue_gemm_v9<_Float16><<<dim3(512), 512, 0, stream>>>(white, black, Wws, P);
        nnue_tail<_Float16><<<dim3(128), 256, 0, stream>>>(P, b_in, w_h1, b_h1,
                                                           w_h2, b_h2, w_out, b_out, out);
    } else {
        nnue_naive<<<4096, 256, 0, stream>>>(white, black, w_in, b_in, w_h1, b_h1,
                                             w_h2, b_h2, w_out, b_out, out);
    }
}

// Round 12
// 390.426 us; speedup vs baseline: 1.0090x; 1.0090x over previous
//
#include <hip/hip_runtime.h>
#include <hip/hip_fp16.h>

// NNUE forward: out = MLP(clip(concat(Wf@w_in^T+b, Bf@w_in^T+b)))
// Big GEMM: M=8192, N=256, K=40960, HBM-bound on the 1.31 GB A stream.
// fp16 MFMA 16x16x32, f32 accumulate.
//
// v10 (r11 post-mortem: v7/v8/v9 all ~385us; the invariant is 160 barrier
// intervals x ~2000cyc fixed overhead on top of 3200cyc HBM service).
// Flatmm (v9) + TWO K-steps per barrier (80 barriers):
//  - each wave owns 16 rows x N=256 (16 accs = 64 VGPR); A loaded directly
//    global->VGPR (8 floats/lane), cvt in-reg, no A-LDS.
//  - W: pre-swizzled f16 image, global_load_lds into 4 x 16KB bufs.
//    Group g (steps t=2g,2g+1): stage W(2g+2)->buf, W(2g+3)->buf (next group's
//    tiles; mod-4 cycle never collides with the two bufs being read);
//    load A(2g+2..3) into the spare reg set; 2x[cvt+16 ds_read+16 MFMA];
//    s_waitcnt vmcnt(4) (retire THIS group's W for cross-wave visibility,
//    keep the 4 A loads in flight) lgkmcnt(0); s_barrier.
//  - 512 thr = 8 waves, KS=8 -> 512 blocks, 2/CU (128 KB LDS);
//    ks=blockIdx&7 -> one 2.6 MB W slice per XCD (L2-resident).

#define FEAT 40960
#define PSTRIDE (8192ull * 256ull)
#define KSPLIT 8
#define KCHUNK (FEAT / KSPLIT)   // 5120
#define NSTEP 160
#define WTILE_BYTES 16384        // 256 rows x 32 k x f16, swizzled
#define WWS_BYTES (1280ull * WTILE_BYTES)   // 20 MB

using floatx4 = __attribute__((ext_vector_type(4))) float;
using half8   = __attribute__((ext_vector_type(8))) _Float16;

// ---------------------------------------------------------------------------
// W pre-pass: w_in f32 [256][40960] -> Wws f16, 1280 chunks of 16 KB, each
// the exact swizzled LDS image for one K-step: byte(r, granule g) =
// T*16384 + r*64 + ((g ^ ((r>>1)&3))*16). T = ks*160 + t (ks-major).
// ---------------------------------------------------------------------------
__global__ __launch_bounds__(256) void nnue_wprep(
    const float* __restrict__ w_in, _Float16* __restrict__ Wws)
{
    const int bid = blockIdx.x;                       // 1280
    const int T   = (bid & 7) * NSTEP + (bid >> 3);
    char* base = (char*)Wws + (size_t)T * WTILE_BYTES;
    const int tid = threadIdx.x;
    const int kg0 = T * 32;
#pragma unroll
    for (int i = 0; i < 4; ++i) {
        const int G = tid + i * 256;                  // 0..1023
        const int r = G >> 2, g = G & 3;
        const float* src = w_in + (size_t)r * FEAT + kg0 + g * 8;
        floatx4 v0 = *reinterpret_cast<const floatx4*>(src);
        floatx4 v1 = *reinterpret_cast<const floatx4*>(src + 4);
        half8 h;
#pragma unroll
        for (int j = 0; j < 4; ++j) { h[j] = (_Float16)v0[j]; h[4 + j] = (_Float16)v1[j]; }
        *reinterpret_cast<half8*>(base + r * 64 + ((g ^ ((r >> 1) & 3)) << 4)) = h;
    }
}

// ---------------------------------------------------------------------------
// Primary GEMM: 512 thr = 8 waves, wave strip = 16 rows x 256 cols.
// ---------------------------------------------------------------------------
template <typename PT>
__global__ __launch_bounds__(512, 4) void nnue_gemm_v10(
    const float* __restrict__ white, const float* __restrict__ black,
    const _Float16* __restrict__ Wws, PT* __restrict__ P)
{
    __shared__ __align__(16) _Float16 Ws[4][256 * 32];   // 64 KB

    const int tid  = threadIdx.x;
    const int lane = tid & 63;
    const int wave = tid >> 6;    // 0..7

    const int ks = blockIdx.x & 7;    // == XCD index (round-robin dispatch)
    const int mb = blockIdx.x >> 3;   // 0..63

    const float* Abase = (mb < 32)
        ? (white + (size_t)mb * 128 * FEAT)
        : (black + (size_t)(mb - 32) * 128 * FEAT);
    const int k0 = ks * KCHUNK;

    const int frow = lane & 15;
    const int fhi  = lane >> 4;

    // A: per-lane row = wave*16 + frow, k window = k0 + t*32 + fhi*8 (8 floats)
    const float* Aptr = Abase + (size_t)(wave * 16 + frow) * FEAT + fhi * 8 + k0;

    // W LDS read byte offset within a row: (fhi*16) ^ (((frow>>1)&3)<<4)
    const int kb = (fhi * 16) ^ (((frow >> 1) & 3) << 4);

    // W async staging: per-lane global src (pre-swizzled), wave-linear LDS
    const char* wsrc0 = (const char*)Wws + (size_t)(ks * NSTEP) * WTILE_BYTES
                        + wave * 2048 + lane * 16;

    floatx4 acc[16];
    const floatx4 zero = {0.f, 0.f, 0.f, 0.f};
#pragma unroll
    for (int n = 0; n < 16; ++n) acc[n] = zero;

    // two statically-named A prefetch sets, each = one GROUP (2 steps)
    floatx4 cA0, cA1, cA2, cA3, nA0, nA1, nA2, nA3;

    auto issueW = [&](int t, int wb) {
        const char* g = wsrc0 + (size_t)t * WTILE_BYTES;
        char* l = (char*)&Ws[wb][0] + wave * 2048;
        __builtin_amdgcn_global_load_lds(
            (const __attribute__((address_space(1))) unsigned int*)g,
            (__attribute__((address_space(3))) unsigned int*)l, 16, 0, 0);
        __builtin_amdgcn_global_load_lds(
            (const __attribute__((address_space(1))) unsigned int*)(g + 1024),
            (__attribute__((address_space(3))) unsigned int*)(l + 1024), 16, 0, 0);
    };

    auto cvt = [&](const floatx4& a0, const floatx4& a1) {
        half8 h;
#pragma unroll
        for (int j = 0; j < 4; ++j) { h[j] = (_Float16)a0[j]; h[4 + j] = (_Float16)a1[j]; }
        return h;
    };

    auto mfmaStep = [&](int wb, half8 af) {
        const char* wbase = (const char*)&Ws[wb][0];
#pragma unroll
        for (int n = 0; n < 16; ++n) {
            half8 bf = *reinterpret_cast<const half8*>(
                wbase + (n * 16 + frow) * 64 + kb);
            acc[n] = __builtin_amdgcn_mfma_f32_16x16x32_f16(af, bf, acc[n], 0, 0, 0);
        }
    };

    // one group = steps (2g, 2g+1). rb0/rb1: bufs read; wb0/wb1: bufs staged
    // (tiles 2g+2, 2g+3). c* = A(2g),A(2g+1); n* <- A(2g+2),A(2g+3).
    auto groupf = [&](int g,
                      floatx4& c0, floatx4& c1, floatx4& c2, floatx4& c3,
                      floatx4& n0, floatx4& n1, floatx4& n2, floatx4& n3,
                      int rb0, int rb1, int wb0, int wb1) {
        const int t0 = 2 * g;
        issueW(t0 + 2, wb0);
        issueW(t0 + 3, wb1);
        __builtin_amdgcn_sched_barrier(0);
        n0 = *reinterpret_cast<const floatx4*>(Aptr + (size_t)(t0 + 2) * 32);
        n1 = *reinterpret_cast<const floatx4*>(Aptr + (size_t)(t0 + 2) * 32 + 4);
        n2 = *reinterpret_cast<const floatx4*>(Aptr + (size_t)(t0 + 3) * 32);
        n3 = *reinterpret_cast<const floatx4*>(Aptr + (size_t)(t0 + 3) * 32 + 4);
        mfmaStep(rb0, cvt(c0, c1));            // cvt waits A(2g): counted vmcnt
        mfmaStep(rb1, cvt(c2, c3));
        // retire this group's W (cross-wave LDS visibility after the barrier);
        // keep the 4 A loads in flight across the barrier.
        asm volatile("s_waitcnt vmcnt(4) lgkmcnt(0)" ::: "memory");
        __builtin_amdgcn_s_barrier();
        __builtin_amdgcn_sched_barrier(0);
    };

    // prologue: W(0)->b0, W(1)->b1 retired; A(0),A(1) in flight
    issueW(0, 0);
    issueW(1, 1);
    __builtin_amdgcn_sched_barrier(0);
    cA0 = *reinterpret_cast<const floatx4*>(Aptr);
    cA1 = *reinterpret_cast<const floatx4*>(Aptr + 4);
    cA2 = *reinterpret_cast<const floatx4*>(Aptr + 32);
    cA3 = *reinterpret_cast<const floatx4*>(Aptr + 32 + 4);
    asm volatile("s_waitcnt vmcnt(4)" ::: "memory");   // W(0),W(1) retired
    __builtin_amdgcn_s_barrier();
    __builtin_amdgcn_sched_barrier(0);

    // groups 0..77 (39 even/odd pairs), all full-body
    for (int p = 0; p < 39; ++p) {
        groupf(2 * p,     cA0, cA1, cA2, cA3, nA0, nA1, nA2, nA3, 0, 1, 2, 3);
        groupf(2 * p + 1, nA0, nA1, nA2, nA3, cA0, cA1, cA2, cA3, 2, 3, 0, 1);
    }
    // group 78 (even): reads bufs 0,1 (t=156,157); stages W158->2, W159->3;
    // loads A(158),A(159) -> nA
    groupf(78, cA0, cA1, cA2, cA3, nA0, nA1, nA2, nA3, 0, 1, 2, 3);
    // group 79 tail: t=158 (buf 2), t=159 (buf 3)
    mfmaStep(2, cvt(nA0, nA1));
    mfmaStep(3, cvt(nA2, nA3));

    // epilogue: partial C. row = wave*16 + fhi*4 + r, col = n*16 + frow
    PT* Pb = P + (size_t)ks * PSTRIDE + (size_t)mb * 128 * 256;
#pragma unroll
    for (int n = 0; n < 16; ++n)
#pragma unroll
        for (int r = 0; r < 4; ++r) {
            const int row = wave * 16 + fhi * 4 + r;
            const int col = n * 16 + frow;
            Pb[(size_t)row * 256 + col] = (PT)acc[n][r];
        }
}

// ---------------------------------------------------------------------------
// Tail: reduce KS partials + b_in + clip -> x[.,512], then the 3 tiny layers.
// One block per 32 batch rows.
// ---------------------------------------------------------------------------
template <typename PT>
__global__ __launch_bounds__(256) void nnue_tail(
    const PT* __restrict__ P,
    const float* __restrict__ b_in,
    const float* __restrict__ w_h1, const float* __restrict__ b_h1,
    const float* __restrict__ w_h2, const float* __restrict__ b_h2,
    const float* __restrict__ w_out, const float* __restrict__ b_out,
    float* __restrict__ out)
{
    __shared__ float xs[32][512];
    __shared__ float w1[32][513];
    __shared__ float w2[32][33];
    __shared__ float h1[32][33];
    __shared__ float h2[32][33];
    __shared__ float wo[32];

    const int tid = threadIdx.x;
    const int b0  = blockIdx.x * 32;

    for (int i = tid; i < 32 * 512; i += 256) w1[i >> 9][i & 511] = w_h1[i];
    for (int i = tid; i < 32 * 32; i += 256)  w2[i >> 5][i & 31]  = w_h2[i];
    if (tid < 32) wo[tid] = w_out[tid];

    for (int i = tid; i < 32 * 512; i += 256) {
        const int r = i >> 9, c = i & 511;
        const int persp = c >> 8, n = c & 255;
        const size_t prow = (size_t)(b0 + r) + (persp ? 4096u : 0u);
        float v = 0.f;
#pragma unroll
        for (int s = 0; s < KSPLIT; ++s)
            v += (float)P[(size_t)s * PSTRIDE + prow * 256 + n];
        v += b_in[n];
        xs[r][c] = fminf(fmaxf(v, 0.f), 1.f);
    }
    __syncthreads();

    for (int p = tid; p < 32 * 32; p += 256) {
        const int o = p & 31, r = p >> 5;
        float a = b_h1[o];
        for (int j = 0; j < 512; ++j) a += xs[r][j] * w1[o][j];
        h1[r][o] = fminf(fmaxf(a, 0.f), 1.f);
    }
    __syncthreads();

    for (int p = tid; p < 32 * 32; p += 256) {
        const int o = p & 31, r = p >> 5;
        float a = b_h2[o];
        for (int j = 0; j < 32; ++j) a += h1[r][j] * w2[o][j];
        h2[r][o] = fminf(fmaxf(a, 0.f), 1.f);
    }
    __syncthreads();

    if (tid < 32) {
        float a = b_out[0];
        for (int j = 0; j < 32; ++j) a += h2[tid][j] * wo[j];
        out[b0 + tid] = a;
    }
}

// ---------------------------------------------------------------------------
// Emergency fallback (ws too small): slow but correct, no scratch.
// ---------------------------------------------------------------------------
__global__ __launch_bounds__(256) void nnue_naive(
    const float* __restrict__ white, const float* __restrict__ black,
    const float* __restrict__ w_in, const float* __restrict__ b_in,
    const float* __restrict__ w_h1, const float* __restrict__ b_h1,
    const float* __restrict__ w_h2, const float* __restrict__ b_h2,
    const float* __restrict__ w_out, const float* __restrict__ b_out,
    float* __restrict__ out)
{
    __shared__ float feat[4096];
    __shared__ float xs[512];
    __shared__ float h1s[32];
    __shared__ float h2s[32];
    const int b = blockIdx.x, tid = threadIdx.x;
    float acc0 = 0.f, acc1 = 0.f;
    for (int c = 0; c < FEAT; c += 2048) {
        for (int i = tid; i < 2048; i += 256) {
            feat[i]        = white[(size_t)b * FEAT + c + i];
            feat[2048 + i] = black[(size_t)b * FEAT + c + i];
        }
        __syncthreads();
        const float* wr = w_in + (size_t)tid * FEAT + c;
        for (int k = 0; k < 2048; ++k) {
            const float w = wr[k];
            acc0 += feat[k] * w;
            acc1 += feat[2048 + k] * w;
        }
        __syncthreads();
    }
    xs[tid]       = fminf(fmaxf(acc0 + b_in[tid], 0.f), 1.f);
    xs[256 + tid] = fminf(fmaxf(acc1 + b_in[tid], 0.f), 1.f);
    __syncthreads();
    if (tid < 32) {
        float a = b_h1[tid];
        for (int j = 0; j < 512; ++j) a += xs[j] * w_h1[tid * 512 + j];
        h1s[tid] = fminf(fmaxf(a, 0.f), 1.f);
    }
    __syncthreads();
    if (tid < 32) {
        float a = b_h2[tid];
        for (int j = 0; j < 32; ++j) a += h1s[j] * w_h2[tid * 32 + j];
        h2s[tid] = fminf(fmaxf(a, 0.f), 1.f);
    }
    __syncthreads();
    if (tid == 0) {
        float a = b_out[0];
        for (int j = 0; j < 32; ++j) a += h2s[j] * w_out[j];
        out[b] = a;
    }
}

extern "C" void kernel_launch(void* const* d_in, const int* in_sizes, int n_in,
                              void* d_out, int out_size, void* d_ws, size_t ws_size,
                              hipStream_t stream)
{
    const float* white = (const float*)d_in[0];
    const float* black = (const float*)d_in[1];
    const float* w_in  = (const float*)d_in[2];
    const float* b_in  = (const float*)d_in[3];
    const float* w_h1  = (const float*)d_in[4];
    const float* b_h1  = (const float*)d_in[5];
    const float* w_h2  = (const float*)d_in[6];
    const float* b_h2  = (const float*)d_in[7];
    const float* w_out = (const float*)d_in[8];
    const float* b_out = (const float*)d_in[9];
    float* out = (float*)d_out;

    const size_t pF32 = KSPLIT * PSTRIDE * sizeof(float);     // 64 MB
    const size_t pF16 = KSPLIT * PSTRIDE * sizeof(_Float16);  // 32 MB

    if (ws_size >= pF32 + WWS_BYTES) {
        float* P = (float*)d_ws;
        _Float16* Wws = (_Float16*)((char*)d_ws + pF32);
        nnue_wprep<<<dim3(1280), 256, 0, stream>>>(w_in, Wws);
        nnue_gemm_v10<float><<<dim3(512), 512, 0, stream>>>(white, black, Wws, P);
        nnue_tail<float><<<dim3(128), 256, 0, stream>>>(P, b_in, w_h1, b_h1,
                                                        w_h2, b_h2, w_out, b_out, out);
    } else if (ws_size >= pF16 + WWS_BYTES) {
        _Float16* P = (_Float16*)d_ws;
        _Float16* Wws = (_Float16*)((char*)d_ws + pF16);
        nnue_wprep<<<dim3(1280), 256, 0, stream>>>(w_in, Wws);
        nnue_gemm_v10<_Float16><<<dim3(512), 512, 0, stream>>>(white, black, Wws, P);
        nnue_tail<_Float16><<<dim3(128), 256, 0, stream>>>(P, b_in, w_h1, b_h1,
                                                           w_h2, b_h2, w_out, b_out, out);
    } else {
        nnue_naive<<<4096, 256, 0, stream>>>(white, black, w_in, b_in, w_h1, b_h1,
                                             w_h2, b_h2, w_out, b_out, out);
    }
}

// Round 13
// 372.536 us; speedup vs baseline: 1.0574x; 1.0480x over previous
//
#include <hip/hip_runtime.h>
#include <hip/hip_fp16.h>

// NNUE forward: out = MLP(clip(concat(Wf@w_in^T+b, Bf@w_in^T+b)))
// Big GEMM: M=8192, N=256, K=40960, HBM-bound on the 1.31 GB A stream.
// fp16 MFMA 16x16x32, f32 accumulate.
//
// v11 (r12 post-mortem: v7/v8/v9/v10 all ~385us across four different
// schedules -> limiter is the ADDRESS PATTERN, not the schedule).
// Theory: A row stride 160 KB = 40 x 4KB aliases all 128 rows of a block
// onto the same DRAM channel-interleave positions, and all blocks sit at
// the same k-phase -> ~8-16 of ~128 channel positions carry all traffic
// (2.7 TB/s ~= 41% of the 6.6 TB/s linear fill rate).
// Fix: per-block K-rotation. Block (mb,ks) starts its K-walk at
// t0 = (mb*37) mod 160 and wraps; GEMM accumulation is order-independent.
// Everything else identical to v10 (flatmm, 2 steps/barrier, 4 W bufs):
//  - wave owns 16 rows x N=256 (16 accs); A global->VGPR->cvt->MFMA.
//  - W pre-swizzled, global_load_lds, vmcnt(4)+lgkmcnt(0) per group.
//  - 512 thr, KS=8 -> 512 blocks, 2/CU; ks=blockIdx&7 -> W slice per XCD.

#define FEAT 40960
#define PSTRIDE (8192ull * 256ull)
#define KSPLIT 8
#define KCHUNK (FEAT / KSPLIT)   // 5120
#define NSTEP 160
#define WTILE_BYTES 16384        // 256 rows x 32 k x f16, swizzled
#define WWS_BYTES (1280ull * WTILE_BYTES)   // 20 MB

using floatx4 = __attribute__((ext_vector_type(4))) float;
using half8   = __attribute__((ext_vector_type(8))) _Float16;

// ---------------------------------------------------------------------------
// W pre-pass: w_in f32 [256][40960] -> Wws f16, 1280 chunks of 16 KB, each
// the exact swizzled LDS image for one K-step: byte(r, granule g) =
// T*16384 + r*64 + ((g ^ ((r>>1)&3))*16). T = ks*160 + t (ks-major).
// ---------------------------------------------------------------------------
__global__ __launch_bounds__(256) void nnue_wprep(
    const float* __restrict__ w_in, _Float16* __restrict__ Wws)
{
    const int bid = blockIdx.x;                       // 1280
    const int T   = (bid & 7) * NSTEP + (bid >> 3);
    char* base = (char*)Wws + (size_t)T * WTILE_BYTES;
    const int tid = threadIdx.x;
    const int kg0 = T * 32;
#pragma unroll
    for (int i = 0; i < 4; ++i) {
        const int G = tid + i * 256;                  // 0..1023
        const int r = G >> 2, g = G & 3;
        const float* src = w_in + (size_t)r * FEAT + kg0 + g * 8;
        floatx4 v0 = *reinterpret_cast<const floatx4*>(src);
        floatx4 v1 = *reinterpret_cast<const floatx4*>(src + 4);
        half8 h;
#pragma unroll
        for (int j = 0; j < 4; ++j) { h[j] = (_Float16)v0[j]; h[4 + j] = (_Float16)v1[j]; }
        *reinterpret_cast<half8*>(base + r * 64 + ((g ^ ((r >> 1) & 3)) << 4)) = h;
    }
}

// ---------------------------------------------------------------------------
// Primary GEMM: 512 thr = 8 waves, wave strip = 16 rows x 256 cols.
// ---------------------------------------------------------------------------
template <typename PT>
__global__ __launch_bounds__(512, 4) void nnue_gemm_v11(
    const float* __restrict__ white, const float* __restrict__ black,
    const _Float16* __restrict__ Wws, PT* __restrict__ P)
{
    __shared__ __align__(16) _Float16 Ws[4][256 * 32];   // 64 KB

    const int tid  = threadIdx.x;
    const int lane = tid & 63;
    const int wave = tid >> 6;    // 0..7

    const int ks = blockIdx.x & 7;    // == XCD index (round-robin dispatch)
    const int mb = blockIdx.x >> 3;   // 0..63

    const float* Abase = (mb < 32)
        ? (white + (size_t)mb * 128 * FEAT)
        : (black + (size_t)(mb - 32) * 128 * FEAT);

    // K-rotation phase: de-alias DRAM channels across blocks.
    const int t0 = (mb * 37) % NSTEP;
    auto wrap = [](int x) { return (x >= NSTEP) ? x - NSTEP : x; };  // x < 2*NSTEP

    const int frow = lane & 15;
    const int fhi  = lane >> 4;

    // A: per-lane row = wave*16 + frow; tile t covers k = ks*KCHUNK + t*32
    const float* Aptr = Abase + (size_t)(wave * 16 + frow) * FEAT + fhi * 8
                        + ks * KCHUNK;

    // W LDS read byte offset within a row: (fhi*16) ^ (((frow>>1)&3)<<4)
    const int kb = (fhi * 16) ^ (((frow >> 1) & 3) << 4);

    // W async staging: per-lane global src (pre-swizzled), wave-linear LDS
    const char* wsrc0 = (const char*)Wws + (size_t)(ks * NSTEP) * WTILE_BYTES
                        + wave * 2048 + lane * 16;

    floatx4 acc[16];
    const floatx4 zero = {0.f, 0.f, 0.f, 0.f};
#pragma unroll
    for (int n = 0; n < 16; ++n) acc[n] = zero;

    // two statically-named A prefetch sets, each = one GROUP (2 tiles)
    floatx4 cA0, cA1, cA2, cA3, nA0, nA1, nA2, nA3;

    auto issueW = [&](int t, int wb) {               // t = wrapped tile index
        const char* g = wsrc0 + (size_t)t * WTILE_BYTES;
        char* l = (char*)&Ws[wb][0] + wave * 2048;
        __builtin_amdgcn_global_load_lds(
            (const __attribute__((address_space(1))) unsigned int*)g,
            (__attribute__((address_space(3))) unsigned int*)l, 16, 0, 0);
        __builtin_amdgcn_global_load_lds(
            (const __attribute__((address_space(1))) unsigned int*)(g + 1024),
            (__attribute__((address_space(3))) unsigned int*)(l + 1024), 16, 0, 0);
    };

    auto cvt = [&](const floatx4& a0, const floatx4& a1) {
        half8 h;
#pragma unroll
        for (int j = 0; j < 4; ++j) { h[j] = (_Float16)a0[j]; h[4 + j] = (_Float16)a1[j]; }
        return h;
    };

    auto mfmaStep = [&](int wb, half8 af) {
        const char* wbase = (const char*)&Ws[wb][0];
#pragma unroll
        for (int n = 0; n < 16; ++n) {
            half8 bf = *reinterpret_cast<const half8*>(
                wbase + (n * 16 + frow) * 64 + kb);
            acc[n] = __builtin_amdgcn_mfma_f32_16x16x32_f16(af, bf, acc[n], 0, 0, 0);
        }
    };

    // one group: consume 2 tiles (A in c*, W in rb0/rb1), prefetch the next
    // group's 2 tiles (tw0, tw1 wrapped) into wb0/wb1 and n*.
    auto groupf = [&](int tw0, int tw1,
                      floatx4& c0, floatx4& c1, floatx4& c2, floatx4& c3,
                      floatx4& n0, floatx4& n1, floatx4& n2, floatx4& n3,
                      int rb0, int rb1, int wb0, int wb1) {
        issueW(tw0, wb0);
        issueW(tw1, wb1);
        __builtin_amdgcn_sched_barrier(0);
        n0 = *reinterpret_cast<const floatx4*>(Aptr + (size_t)tw0 * 32);
        n1 = *reinterpret_cast<const floatx4*>(Aptr + (size_t)tw0 * 32 + 4);
        n2 = *reinterpret_cast<const floatx4*>(Aptr + (size_t)tw1 * 32);
        n3 = *reinterpret_cast<const floatx4*>(Aptr + (size_t)tw1 * 32 + 4);
        mfmaStep(rb0, cvt(c0, c1));            // cvt waits its A: counted vmcnt
        mfmaStep(rb1, cvt(c2, c3));
        // retire this group's W (cross-wave LDS visibility after the barrier);
        // keep the 4 A loads in flight across the barrier.
        asm volatile("s_waitcnt vmcnt(4) lgkmcnt(0)" ::: "memory");
        __builtin_amdgcn_s_barrier();
        __builtin_amdgcn_sched_barrier(0);
    };

    // prologue: tiles i=0,1 (wrapped) -> bufs 0,1 retired; their A in regs
    {
        const int p0 = t0;                 // wrap(t0) == t0
        const int p1 = wrap(t0 + 1);
        issueW(p0, 0);
        issueW(p1, 1);
        __builtin_amdgcn_sched_barrier(0);
        cA0 = *reinterpret_cast<const floatx4*>(Aptr + (size_t)p0 * 32);
        cA1 = *reinterpret_cast<const floatx4*>(Aptr + (size_t)p0 * 32 + 4);
        cA2 = *reinterpret_cast<const floatx4*>(Aptr + (size_t)p1 * 32);
        cA3 = *reinterpret_cast<const floatx4*>(Aptr + (size_t)p1 * 32 + 4);
        asm volatile("s_waitcnt vmcnt(4)" ::: "memory");   // W(i0),W(i1) retired
        __builtin_amdgcn_s_barrier();
        __builtin_amdgcn_sched_barrier(0);
    }

    // groups 0..77 (39 even/odd pairs); group g prefetches iterations 2g+2,2g+3
    for (int p = 0; p < 39; ++p) {
        const int i0 = 4 * p;
        groupf(wrap(t0 + i0 + 2), wrap(t0 + i0 + 3),
               cA0, cA1, cA2, cA3, nA0, nA1, nA2, nA3, 0, 1, 2, 3);
        groupf(wrap(t0 + i0 + 4), wrap(t0 + i0 + 5),
               nA0, nA1, nA2, nA3, cA0, cA1, cA2, cA3, 2, 3, 0, 1);
    }
    // group 78: reads bufs 0,1 (iters 156,157); prefetch iters 158,159
    groupf(wrap(t0 + 158), wrap(t0 + 159),
           cA0, cA1, cA2, cA3, nA0, nA1, nA2, nA3, 0, 1, 2, 3);
    // group 79 tail: iters 158 (buf 2), 159 (buf 3)
    mfmaStep(2, cvt(nA0, nA1));
    mfmaStep(3, cvt(nA2, nA3));

    // epilogue: partial C. row = wave*16 + fhi*4 + r, col = n*16 + frow
    PT* Pb = P + (size_t)ks * PSTRIDE + (size_t)mb * 128 * 256;
#pragma unroll
    for (int n = 0; n < 16; ++n)
#pragma unroll
        for (int r = 0; r < 4; ++r) {
            const int row = wave * 16 + fhi * 4 + r;
            const int col = n * 16 + frow;
            Pb[(size_t)row * 256 + col] = (PT)acc[n][r];
        }
}

// ---------------------------------------------------------------------------
// Tail: reduce KS partials + b_in + clip -> x[.,512], then the 3 tiny layers.
// One block per 32 batch rows.
// ---------------------------------------------------------------------------
template <typename PT>
__global__ __launch_bounds__(256) void nnue_tail(
    const PT* __restrict__ P,
    const float* __restrict__ b_in,
    const float* __restrict__ w_h1, const float* __restrict__ b_h1,
    const float* __restrict__ w_h2, const float* __restrict__ b_h2,
    const float* __restrict__ w_out, const float* __restrict__ b_out,
    float* __restrict__ out)
{
    __shared__ float xs[32][512];
    __shared__ float w1[32][513];
    __shared__ float w2[32][33];
    __shared__ float h1[32][33];
    __shared__ float h2[32][33];
    __shared__ float wo[32];

    const int tid = threadIdx.x;
    const int b0  = blockIdx.x * 32;

    for (int i = tid; i < 32 * 512; i += 256) w1[i >> 9][i & 511] = w_h1[i];
    for (int i = tid; i < 32 * 32; i += 256)  w2[i >> 5][i & 31]  = w_h2[i];
    if (tid < 32) wo[tid] = w_out[tid];

    for (int i = tid; i < 32 * 512; i += 256) {
        const int r = i >> 9, c = i & 511;
        const int persp = c >> 8, n = c & 255;
        const size_t prow = (size_t)(b0 + r) + (persp ? 4096u : 0u);
        float v = 0.f;
#pragma unroll
        for (int s = 0; s < KSPLIT; ++s)
            v += (float)P[(size_t)s * PSTRIDE + prow * 256 + n];
        v += b_in[n];
        xs[r][c] = fminf(fmaxf(v, 0.f), 1.f);
    }
    __syncthreads();

    for (int p = tid; p < 32 * 32; p += 256) {
        const int o = p & 31, r = p >> 5;
        float a = b_h1[o];
        for (int j = 0; j < 512; ++j) a += xs[r][j] * w1[o][j];
        h1[r][o] = fminf(fmaxf(a, 0.f), 1.f);
    }
    __syncthreads();

    for (int p = tid; p < 32 * 32; p += 256) {
        const int o = p & 31, r = p >> 5;
        float a = b_h2[o];
        for (int j = 0; j < 32; ++j) a += h1[r][j] * w2[o][j];
        h2[r][o] = fminf(fmaxf(a, 0.f), 1.f);
    }
    __syncthreads();

    if (tid < 32) {
        float a = b_out[0];
        for (int j = 0; j < 32; ++j) a += h2[tid][j] * wo[j];
        out[b0 + tid] = a;
    }
}

// ---------------------------------------------------------------------------
// Emergency fallback (ws too small): slow but correct, no scratch.
// ---------------------------------------------------------------------------
__global__ __launch_bounds__(256) void nnue_naive(
    const float* __restrict__ white, const float* __restrict__ black,
    const float* __restrict__ w_in, const float* __restrict__ b_in,
    const float* __restrict__ w_h1, const float* __restrict__ b_h1,
    const float* __restrict__ w_h2, const float* __restrict__ b_h2,
    const float* __restrict__ w_out, const float* __restrict__ b_out,
    float* __restrict__ out)
{
    __shared__ float feat[4096];
    __shared__ float xs[512];
    __shared__ float h1s[32];
    __shared__ float h2s[32];
    const int b = blockIdx.x, tid = threadIdx.x;
    float acc0 = 0.f, acc1 = 0.f;
    for (int c = 0; c < FEAT; c += 2048) {
        for (int i = tid; i < 2048; i += 256) {
            feat[i]        = white[(size_t)b * FEAT + c + i];
            feat[2048 + i] = black[(size_t)b * FEAT + c + i];
        }
        __syncthreads();
        const float* wr = w_in + (size_t)tid * FEAT + c;
        for (int k = 0; k < 2048; ++k) {
            const float w = wr[k];
            acc0 += feat[k] * w;
            acc1 += feat[2048 + k] * w;
        }
        __syncthreads();
    }
    xs[tid]       = fminf(fmaxf(acc0 + b_in[tid], 0.f), 1.f);
    xs[256 + tid] = fminf(fmaxf(acc1 + b_in[tid], 0.f), 1.f);
    __syncthreads();
    if (tid < 32) {
        float a = b_h1[tid];
        for (int j = 0; j < 512; ++j) a += xs[j] * w_h1[tid * 512 + j];
        h1s[tid] = fminf(fmaxf(a, 0.f), 1.f);
    }
    __syncthreads();
    if (tid < 32) {
        float a = b_h2[tid];
        for (int j = 0; j < 32; ++j) a += h1s[j] * w_h2[tid * 32 + j];
        h2s[tid] = fminf(fmaxf(a, 0.f), 1.f);
    }
    __syncthreads();
    if (tid == 0) {
        float a = b_out[0];
        for (int j = 0; j < 32; ++j) a += h2s[j] * w_out[j];
        out[b] = a;
    }
}

extern "C" void kernel_launch(void* const* d_in, const int* in_sizes, int n_in,
                              void* d_out, int out_size, void* d_ws, size_t ws_size,
                              hipStream_t stream)
{
    const float* white = (const float*)d_in[0];
    const float* black = (const float*)d_in[1];
    const float* w_in  = (const float*)d_in[2];
    const float* b_in  = (const float*)d_in[3];
    const float* w_h1  = (const float*)d_in[4];
    const float* b_h1  = (const float*)d_in[5];
    const float* w_h2  = (const float*)d_in[6];
    const float* b_h2  = (const float*)d_in[7];
    const float* w_out = (const float*)d_in[8];
    const float* b_out = (const float*)d_in[9];
    float* out = (float*)d_out;

    const size_t pF32 = KSPLIT * PSTRIDE * sizeof(float);     // 64 MB
    const size_t pF16 = KSPLIT * PSTRIDE * sizeof(_Float16);  // 32 MB

    if (ws_size >= pF32 + WWS_BYTES) {
        float* P = (float*)d_ws;
        _Float16* Wws = (_Float16*)((char*)d_ws + pF32);
        nnue_wprep<<<dim3(1280), 256, 0, stream>>>(w_in, Wws);
        nnue_gemm_v11<float><<<dim3(512), 512, 0, stream>>>(white, black, Wws, P);
        nnue_tail<float><<<dim3(128), 256, 0, stream>>>(P, b_in, w_h1, b_h1,
                                                        w_h2, b_h2, w_out, b_out, out);
    } else if (ws_size >= pF16 + WWS_BYTES) {
        _Float16* P = (_Float16*)d_ws;
        _Float16* Wws = (_Float16*)((char*)d_ws + pF16);
        nnue_wprep<<<dim3(1280), 256, 0, stream>>>(w_in, Wws);
        nnue_gemm_v11<_Float16><<<dim3(512), 512, 0, stream>>>(white, black, Wws, P);
        nnue_tail<_Float16><<<dim3(128), 256, 0, stream>>>(P, b_in, w_h1, b_h1,
                                                           w_h2, b_h2, w_out, b_out, out);
    } else {
        nnue_naive<<<4096, 256, 0, stream>>>(white, black, w_in, b_in, w_h1, b_h1,
                                             w_h2, b_h2, w_out, b_out, out);
    }
}